// Round 7
// baseline (324.531 us; speedup 1.0000x reference)
//
#include <hip/hip_runtime.h>
#include <hip/hip_bf16.h>
#include <math.h>

// Problem constants
#define BB 32
#define NN 256
#define FF 12
// ws layout (in floats)
#define WS_PART   0                    // 262144: colstats partials [256blk][4][256j]
#define WS_STATS  262144               // 1024: mean_d, istd_d, mean_r, istd_r
#define WS_W2P    263168               // 1024: W2 repacked [32k][32m] (m padded)
#define WS_B2P    264192               // 64: b2 padded
#define WS_USG    264256               // 262144: us[b][i][32]
#define WS_UTPG   526400               // 262144: ut'[b][j][32]
#define WS_MIN    788544               // 1048576: minusv[b][jq][i][32]
#define WS_PLUS   1837120              // nit*262144: plus_T[b][it][j][32]

typedef __attribute__((ext_vector_type(8))) short bf16x8;
typedef __attribute__((ext_vector_type(4))) float f32x4;

// fast sigmoid: v_exp_f32 + v_rcp_f32
__device__ __forceinline__ float sig(float x) {
    return __builtin_amdgcn_rcpf(1.0f + __expf(-x));
}
__device__ __forceinline__ short f2bf(float x) {
    __hip_bfloat16 b = __float2bfloat16(x);   // RTNE (weights only)
    short s; __builtin_memcpy(&s, &b, 2); return s;
}
__device__ __forceinline__ float bf2f(short s) {
    __hip_bfloat16 b; __builtin_memcpy(&b, &s, 2);
    return __bfloat162float(b);
}
// truncation pair-pack: two f32 -> two bf16 in one u32
__device__ __forceinline__ unsigned pkbf(float lo, float hi) {
    unsigned ulo, uhi;
    __builtin_memcpy(&ulo, &lo, 4); __builtin_memcpy(&uhi, &hi, 4);
    return (uhi & 0xffff0000u) | (ulo >> 16);
}

// ---- K1: colstats partials (blocks 0-255) || node projections (256-1279) ----
__global__ __launch_bounds__(256) void pre_kernel(
    const float* __restrict__ dist, const float* __restrict__ direc,
    const float* __restrict__ x, const float* __restrict__ W1,
    const float* __restrict__ b1, float* __restrict__ partial,
    float* __restrict__ usg, float* __restrict__ utpg)
{
    const int t = threadIdx.x;
    if (blockIdx.x < 256) {
        const int r0 = blockIdx.x * 32;
        float sd = 0.f, sdd = 0.f, sr = 0.f, srr = 0.f;
#pragma unroll 4
        for (int rr = 0; rr < 32; ++rr) {
            const float d  = dist [(r0 + rr) * NN + t];
            const float dr = direc[(r0 + rr) * NN + t];
            sd += d;  sdd = fmaf(d, d, sdd);
            sr += dr; srr = fmaf(dr, dr, srr);
        }
        float* p = partial + blockIdx.x * 1024;
        p[t] = sd; p[256 + t] = sdd; p[512 + t] = sr; p[768 + t] = srr;
    } else {
        const int idx = (blockIdx.x - 256) * 256 + t;   // < 262144
        const int r = idx >> 5, k = idx & 31;
        const float* xr = x + r * FF;
        float us = 0.f, ut = 0.f;
#pragma unroll
        for (int f = 0; f < FF; ++f) {
            const float xv = xr[f];
            us = fmaf(xv, W1[f * 32 + k], us);
            ut = fmaf(xv, W1[(13 + f) * 32 + k], ut);
        }
        const float ca = W1[12 * 32 + k] + W1[25 * 32 + k] + W1[27 * 32 + k]
                       + W1[29 * 32 + k] + W1[30 * 32 + k] + W1[31 * 32 + k];
        usg[idx]  = us;
        utpg[idx] = ut + ca + b1[k];
    }
}

// ---- K2: finalize stats (ddof=1; blocks 0-7, 32 j each) + W2 repack (block 8) ----
__global__ __launch_bounds__(256) void finalize_kernel(
    const float* __restrict__ partial, const float* __restrict__ W2,
    const float* __restrict__ b2, float* __restrict__ stats,
    float* __restrict__ W2p, float* __restrict__ b2p)
{
    const int t = threadIdx.x;
    if (blockIdx.x == 8) {
        for (int idx = t; idx < 1024; idx += 256) {
            const int k = idx >> 5, m = idx & 31;
            W2p[idx] = (m < 30) ? W2[k * 30 + m] : 0.0f;
        }
        if (t < 32) b2p[t] = (t < 30) ? b2[t] : 0.0f;
        return;
    }
    __shared__ float red[4][8][32];
    const int jl = t & 31;
    const int c  = t >> 5;                 // 8 chunks of 32 colstats-blocks
    const int j  = blockIdx.x * 32 + jl;
    float s0 = 0.f, s1 = 0.f, s2 = 0.f, s3 = 0.f;
    for (int bk = c; bk < 256; bk += 8) {
        const float* p = partial + bk * 1024;
        s0 += p[j]; s1 += p[256 + j]; s2 += p[512 + j]; s3 += p[768 + j];
    }
    red[0][c][jl] = s0; red[1][c][jl] = s1; red[2][c][jl] = s2; red[3][c][jl] = s3;
    __syncthreads();
    if (t < 32) {
        float a0 = 0.f, a1 = 0.f, a2 = 0.f, a3 = 0.f;
#pragma unroll
        for (int cc = 0; cc < 8; ++cc) {
            a0 += red[0][cc][t]; a1 += red[1][cc][t];
            a2 += red[2][cc][t]; a3 += red[3][cc][t];
        }
        const float M = (float)(BB * NN);
        const int jj = blockIdx.x * 32 + t;
        {   const float mean = a0 / M;
            float var = (a1 - a0 * mean) / (M - 1.0f);
            if (var < 1e-20f) var = 1e-20f;
            stats[jj] = mean; stats[256 + jj] = rsqrtf(var); }
        {   const float mean = a2 / M;
            float var = (a3 - a2 * mean) / (M - 1.0f);
            if (var < 1e-20f) var = 1e-20f;
            stats[512 + jj] = mean; stats[768 + jj] = rsqrtf(var); }
    }
}

// ---- K3: edge kernel. Block = (b, it, jq): i in [it*R,+R), j in [jq*64,+64).
// Wave w owns 16 j = jq*64 + w*16 + [0,16). Lane l: m0=l&15 (A-row j / D-col m),
// g=l>>4 (k-chunk 8g..8g+7). A,B packed with same (g,e)->k map (HW order cancels).
// D (m89): col m = m0+16mt, row j_loc = 4g+r. No staging sync; one sync pre-flush.
__global__ __launch_bounds__(256, 8) void edge_mfma_kernel(
    const float* __restrict__ adj_dist, const float* __restrict__ adj_direct,
    const float* __restrict__ W1, const float* __restrict__ b1,
    const float* __restrict__ usg, const float* __restrict__ utpg,
    const float* __restrict__ stats, const float* __restrict__ W2p,
    const float* __restrict__ b2p, float* __restrict__ plusT,
    float* __restrict__ minusv, int lognit)
{
    __shared__ float mins[32][4][32];      // 16 KB max (R<=32)

    const int t   = threadIdx.x;
    const int R   = NN >> lognit;          // 16 (lognit=4) or 32
    const int jq  = blockIdx.x & 3;
    const int bit = blockIdx.x >> 2;
    const int b   = bit >> lognit;
    const int it  = bit & ((1 << lognit) - 1);
    const int i0  = it * R;
    const int w   = t >> 6;
    const int l   = t & 63;
    const int m0  = l & 15;
    const int g   = l >> 4;
    const int kb  = g << 3;
    const int j   = (jq << 6) + (w << 4) + m0;   // this lane's input j

    // loop invariants (k = kb..kb+7)
    float b1c[8], r26c[8], r28c[8];
#pragma unroll
    for (int e = 0; e < 8; ++e) {
        b1c[e]  = b1[kb + e];
        r26c[e] = W1[26 * 32 + kb + e];
        r28c[e] = W1[28 * 32 + kb + e];
    }
    float utpc[8];
    { const float4* uv = (const float4*)(utpg + ((b << 8) + j) * 32 + kb);
      const float4 a0 = uv[0], a1 = uv[1];
      utpc[0]=a0.x; utpc[1]=a0.y; utpc[2]=a0.z; utpc[3]=a0.w;
      utpc[4]=a1.x; utpc[5]=a1.y; utpc[6]=a1.z; utpc[7]=a1.w; }
    const float md  = stats[j],       isd = stats[256 + j];
    const float mr  = stats[512 + j], isr = stats[768 + j];

    bf16x8 whi[2], wlo[2];                 // W2 hi/lo split: f32-accurate product
#pragma unroll
    for (int mt = 0; mt < 2; ++mt) {
        const int m = m0 + (mt << 4);
#pragma unroll
        for (int e = 0; e < 8; ++e) {
            const float wv = W2p[(kb + e) * 32 + m];
            const short h16 = f2bf(wv);
            whi[mt][e] = h16;
            wlo[mt][e] = f2bf(wv - bf2f(h16));
        }
    }
    const float b2c[2] = { b2p[m0], b2p[m0 + 16] };
    const bool mt1ok = (m0 < 14);          // m = m0+16 valid iff < 30

    float accp[2][4];
#pragma unroll
    for (int mt = 0; mt < 2; ++mt)
#pragma unroll
        for (int r = 0; r < 4; ++r) accp[mt][r] = 0.0f;

    const float* dptr  = adj_dist   + (((b << 8) + i0) << 8) + j;
    const float* rptr  = adj_direct + (((b << 8) + i0) << 8) + j;
    const float* usrow = usg + ((b << 8) + i0) * 32 + kb;
    float dN = dptr[0], rN = rptr[0];

#pragma unroll 1
    for (int i = 0; i < R; ++i) {
        const float dv = dN, rv = rN;
        if (i + 1 < R) { dN = dptr[(i + 1) << 8]; rN = rptr[(i + 1) << 8]; }

        // us chunk for row i (wave-uniform per g-group: broadcast L1 load)
        const float4 u0 = *(const float4*)(usrow + i * 32);
        const float4 u1 = *(const float4*)(usrow + i * 32 + 4);
        const float usc[8] = {u0.x,u0.y,u0.z,u0.w,u1.x,u1.y,u1.z,u1.w};

        const bool  a  = (dv != 0.0f);
        const float dn = (dv - md) * isd;
        const float rn = (rv - mr) * isr;

        float h[8];
#pragma unroll
        for (int e = 0; e < 8; ++e) {
            float z = a ? (usc[e] + utpc[e]) : b1c[e];
            z = fmaf(dn, r26c[e], z);
            z = fmaf(rn, r28c[e], z);
            h[e] = sig(z);
        }
        union { bf16x8 v; unsigned u[4]; } af;
#pragma unroll
        for (int p = 0; p < 4; ++p) af.u[p] = pkbf(h[2*p], h[2*p+1]);

        float msum0 = 0.0f, msum1 = 0.0f;
#pragma unroll
        for (int mt = 0; mt < 2; ++mt) {
            f32x4 d4 = { b2c[mt], b2c[mt], b2c[mt], b2c[mt] };
            d4 = __builtin_amdgcn_mfma_f32_16x16x32_bf16(af.v, wlo[mt], d4, 0, 0, 0);
            d4 = __builtin_amdgcn_mfma_f32_16x16x32_bf16(af.v, whi[mt], d4, 0, 0, 0);
#pragma unroll
            for (int r = 0; r < 4; ++r) {
                float e = sig(d4[r]);
                if (mt == 1 && !mt1ok) e = 0.0f;
                accp[mt][r] += e;
                if (mt == 0) msum0 += e; else msum1 += e;
            }
        }
        // minus partial: sum over k-groups -> full 16-j wave sum per m
        msum0 += __shfl_xor(msum0, 16); msum0 += __shfl_xor(msum0, 32);
        msum1 += __shfl_xor(msum1, 16); msum1 += __shfl_xor(msum1, 32);
        if (l < 16) { mins[i][w][l] = msum0; mins[i][w][l + 16] = msum1; }
    }
    __syncthreads();

    // minus flush: partial over this block's 64 j, rows i0..i0+R-1 (disjoint per it)
    for (int idx = t; idx < (R << 5); idx += 256) {
        const int ii = idx >> 5, m = idx & 31;
        const float s = mins[ii][0][m] + mins[ii][1][m]
                      + mins[ii][2][m] + mins[ii][3][m];
        minusv[((((b << 2) + jq) << 8) + i0 + ii) * 32 + m] = s;
    }

    // plus store: lane-direct to plus_T[b][it][j][m] (64B-coalesced per 16-lane group)
    { float* pT = plusT + ((size_t)((b << lognit) + it) << 13);
#pragma unroll
      for (int mt = 0; mt < 2; ++mt) {
          const int m = m0 + (mt << 4);
#pragma unroll
          for (int r = 0; r < 4; ++r) {
              const int jo = (jq << 6) + (w << 4) + (g << 2) + r;   // output j
              pT[jo * 32 + m] = accp[mt][r];
          }
      }
    }
}

// ---- K4: reduce partials + node MLP, fused; grid = BB*8 ----
__global__ __launch_bounds__(256) void reduce_out_kernel(
    const float* __restrict__ plusT, const float* __restrict__ minusv,
    const float* __restrict__ W3, const float* __restrict__ b3,
    float* __restrict__ out, int lognit)
{
    __shared__ float agg_s[32][36];        // stride 36: 16B-aligned float4 slots
    const int b   = blockIdx.x >> 3;
    const int nh  = blockIdx.x & 7;
    const int t   = threadIdx.x;
    const int nl  = t & 31;
    const int mq  = t >> 5;                // m-quad: m = 4mq..4mq+3
    const int n   = (nh << 5) + nl;
    const int nit = 1 << lognit;

    f32x4 acc = {0.f, 0.f, 0.f, 0.f};
#pragma unroll 1
    for (int itb = 0; itb < nit; ++itb)
        acc += *(const f32x4*)(plusT + ((size_t)((b << lognit) + itb) << 13)
                               + n * 32 + (mq << 2));
#pragma unroll
    for (int jq = 0; jq < 4; ++jq)
        acc -= *(const f32x4*)(minusv + ((((b << 2) + jq) << 8) + n) * 32 + (mq << 2));
    *(f32x4*)&agg_s[nl][mq << 2] = acc;    // m>=30 slots are exact zeros by constr.
    __syncthreads();

    // node MLP: 32 n x 12 o = 384 tasks
    for (int task = t; task < 384; task += 256) {
        const int n2 = task / 12, o = task % 12;
        float z = b3[o];
#pragma unroll
        for (int m = 0; m < 30; ++m) z = fmaf(agg_s[n2][m], W3[m * 12 + o], z);
        out[(((b << 8) + (nh << 5) + n2) * 12) + o] = sig(z);
    }
}

extern "C" void kernel_launch(void* const* d_in, const int* in_sizes, int n_in,
                              void* d_out, int out_size, void* d_ws, size_t ws_size,
                              hipStream_t stream)
{
    const float* x    = (const float*)d_in[0];
    const float* adjd = (const float*)d_in[1];
    const float* adjr = (const float*)d_in[2];
    const float* W1   = (const float*)d_in[5];
    const float* b1   = (const float*)d_in[6];
    const float* W2   = (const float*)d_in[7];
    const float* b2   = (const float*)d_in[8];
    const float* W3   = (const float*)d_in[9];
    const float* b3   = (const float*)d_in[10];
    float* ws  = (float*)d_ws;
    float* out = (float*)d_out;

    // lognit=4 (R=16, 2048 edge blocks) needs 24.2 MB ws; fall back to lognit=3.
    int lognit = 4;
    if (ws_size < ((size_t)WS_PLUS + 16u * 262144u) * 4u) lognit = 3;

    pre_kernel<<<1280, 256, 0, stream>>>(adjd, adjr, x, W1, b1,
                                         ws + WS_PART, ws + WS_USG, ws + WS_UTPG);
    finalize_kernel<<<9, 256, 0, stream>>>(ws + WS_PART, W2, b2,
                                           ws + WS_STATS, ws + WS_W2P, ws + WS_B2P);
    edge_mfma_kernel<<<(BB << lognit) << 2, 256, 0, stream>>>(
        adjd, adjr, W1, b1, ws + WS_USG, ws + WS_UTPG,
        ws + WS_STATS, ws + WS_W2P, ws + WS_B2P,
        ws + WS_PLUS, ws + WS_MIN, lognit);
    reduce_out_kernel<<<BB * 8, 256, 0, stream>>>(ws + WS_PLUS, ws + WS_MIN,
                                                  W3, b3, out, lognit);
}

// Round 13
// 295.924 us; speedup vs baseline: 1.0967x; 1.0967x over previous
//
#include <hip/hip_runtime.h>
#include <hip/hip_bf16.h>
#include <math.h>

// Problem constants
#define BB 32
#define NN 256
#define FF 12
// ws layout (floats); total 6,031,424 = 24.125 MB — EXACTLY round-7's proven footprint
#define WS_PART   0           // 262144: colstats partials [256blk][4][256j]
#define WS_STATS  262144      // 1024: mean_d, istd_d, mean_r, istd_r
#define WS_W2P    263168      // 1024: W2 repacked [32k][32m]
#define WS_B2P    264192      // 64: b2 padded
#define WS_USG    264256      // 262144: us[b][i][32]
#define WS_UTPG   526400      // 262144: ut'[b][j][32]
#define WS_MIN    788544      // 1048576: minusv[b][jq][m][n]
#define WS_PLUS   1837120     // 4194304: plus[b][it][m][j]  (nit=16)

typedef __attribute__((ext_vector_type(8))) short bf16x8;
typedef __attribute__((ext_vector_type(4))) float f32x4;

__device__ __forceinline__ float sig(float x) {
    return __builtin_amdgcn_rcpf(1.0f + __expf(-x));
}
__device__ __forceinline__ short f2bf(float x) {
    __hip_bfloat16 b = __float2bfloat16(x);   // RTNE (weights only)
    short s; __builtin_memcpy(&s, &b, 2); return s;
}
__device__ __forceinline__ float bf2f(short s) {
    __hip_bfloat16 b; __builtin_memcpy(&b, &s, 2);
    return __bfloat162float(b);
}
__device__ __forceinline__ unsigned pkbf(float lo, float hi) {
    unsigned ulo, uhi;
    __builtin_memcpy(&ulo, &lo, 4); __builtin_memcpy(&uhi, &hi, 4);
    return (uhi & 0xffff0000u) | (ulo >> 16);
}

// ---- K1: colstats partials (blocks 0-255, 32 rows each) || node proj (256-1279) ----
__global__ __launch_bounds__(256) void pre_kernel(
    const float* __restrict__ dist, const float* __restrict__ direc,
    const float* __restrict__ x, const float* __restrict__ W1,
    const float* __restrict__ b1, float* __restrict__ partial,
    float* __restrict__ usg, float* __restrict__ utpg)
{
    const int t = threadIdx.x;
    if (blockIdx.x < 256) {
        const int r0 = blockIdx.x * 32;
        float sd = 0.f, sdd = 0.f, sr = 0.f, srr = 0.f;
#pragma unroll 4
        for (int rr = 0; rr < 32; ++rr) {
            const float d  = dist [(r0 + rr) * NN + t];
            const float dr = direc[(r0 + rr) * NN + t];
            sd += d;  sdd = fmaf(d, d, sdd);
            sr += dr; srr = fmaf(dr, dr, srr);
        }
        float* p = partial + blockIdx.x * 1024;
        p[t] = sd; p[256 + t] = sdd; p[512 + t] = sr; p[768 + t] = srr;
    } else {
        const int idx = (blockIdx.x - 256) * 256 + t;   // < 262144
        const int r = idx >> 5, k = idx & 31;
        const float* xr = x + r * FF;
        float us = 0.f, ut = 0.f;
#pragma unroll
        for (int f = 0; f < FF; ++f) {
            const float xv = xr[f];
            us = fmaf(xv, W1[f * 32 + k], us);
            ut = fmaf(xv, W1[(13 + f) * 32 + k], ut);
        }
        const float ca = W1[12 * 32 + k] + W1[25 * 32 + k] + W1[27 * 32 + k]
                       + W1[29 * 32 + k] + W1[30 * 32 + k] + W1[31 * 32 + k];
        usg[idx]  = us;
        utpg[idx] = ut + ca + b1[k];
    }
}

// ---- K2: finalize stats (ddof=1; blocks 0-7) + W2 repack (block 8) ----
__global__ __launch_bounds__(256) void finalize_kernel(
    const float* __restrict__ partial, const float* __restrict__ W2,
    const float* __restrict__ b2, float* __restrict__ stats,
    float* __restrict__ W2p, float* __restrict__ b2p)
{
    const int t = threadIdx.x;
    if (blockIdx.x == 8) {
        for (int idx = t; idx < 1024; idx += 256) {
            const int k = idx >> 5, m = idx & 31;
            W2p[idx] = (m < 30) ? W2[k * 30 + m] : 0.0f;
        }
        if (t < 32) b2p[t] = (t < 30) ? b2[t] : 0.0f;
        return;
    }
    __shared__ float red[4][8][32];
    const int jl = t & 31;
    const int c  = t >> 5;
    const int j  = blockIdx.x * 32 + jl;
    float s0 = 0.f, s1 = 0.f, s2 = 0.f, s3 = 0.f;
    for (int bk = c; bk < 256; bk += 8) {
        const float* p = partial + bk * 1024;
        s0 += p[j]; s1 += p[256 + j]; s2 += p[512 + j]; s3 += p[768 + j];
    }
    red[0][c][jl] = s0; red[1][c][jl] = s1; red[2][c][jl] = s2; red[3][c][jl] = s3;
    __syncthreads();
    if (t < 32) {
        float a0 = 0.f, a1 = 0.f, a2 = 0.f, a3 = 0.f;
#pragma unroll
        for (int cc = 0; cc < 8; ++cc) {
            a0 += red[0][cc][t]; a1 += red[1][cc][t];
            a2 += red[2][cc][t]; a3 += red[3][cc][t];
        }
        const float M = (float)(BB * NN);
        const int jj = blockIdx.x * 32 + t;
        {   const float mean = a0 / M;
            float var = (a1 - a0 * mean) / (M - 1.0f);
            if (var < 1e-20f) var = 1e-20f;
            stats[jj] = mean; stats[256 + jj] = rsqrtf(var); }
        {   const float mean = a2 / M;
            float var = (a3 - a2 * mean) / (M - 1.0f);
            if (var < 1e-20f) var = 1e-20f;
            stats[512 + jj] = mean; stats[768 + jj] = rsqrtf(var); }
    }
}

// ---- K3: edge kernel. Grid 2048 = b(5b) x it(4b) x jq(2b): 32*16*4 — FULLY enumerated.
// Block: i in [it*16,+16), j in [jq*64,+64). 4 waves x 16 j each.
// Lane l: m0=l&15 (A-row j / D-col m), g=l>>4 (k-chunk 8g..8g+7); lane owns its j directly.
// A,B packed with same (g,e)->k map (HW k-order cancels).
// D (m89): col m = m0+16mt, row j_loc = 4g+r.
// LDS: us_s staged once; mins (pre-sync) and ldst (post-sync) share a union (8 KB).
union LdsPool { float mins[16][4][32]; float ldst[30][65]; };

__global__ __launch_bounds__(256, 8) void edge_mfma_kernel(
    const float* __restrict__ adj_dist, const float* __restrict__ adj_direct,
    const float* __restrict__ W1, const float* __restrict__ b1,
    const float* __restrict__ usg, const float* __restrict__ utpg,
    const float* __restrict__ stats, const float* __restrict__ W2p,
    const float* __restrict__ b2p, float* __restrict__ plus,
    float* __restrict__ minusv)
{
    __shared__ float us_s[16][32];       // 2 KB
    __shared__ LdsPool pool;             // 8 KB

    const int t   = threadIdx.x;
    const int bid = blockIdx.x;
    const int jq  = bid & 3;
    const int it  = (bid >> 2) & 15;
    const int b   = bid >> 6;            // < 32  (2048 = 32*16*4, fully covered)
    const int i0  = it << 4;
    const int w   = t >> 6;
    const int l   = t & 63;
    const int m0  = l & 15;
    const int g   = l >> 4;
    const int kb  = g << 3;
    const int j   = (jq << 6) + (w << 4) + m0;   // this lane's j (owned directly)

    { const int k = t & 31;
      for (int ii = t >> 5; ii < 16; ii += 8)
          us_s[ii][k] = usg[((b << 8) + i0 + ii) * 32 + k]; }
    __syncthreads();

    float b1c[8], r26c[8], r28c[8];
#pragma unroll
    for (int e = 0; e < 8; ++e) {
        b1c[e]  = b1[kb + e];
        r26c[e] = W1[26 * 32 + kb + e];
        r28c[e] = W1[28 * 32 + kb + e];
    }
    float utpc[8];
    { const float4* uv = (const float4*)(utpg + ((b << 8) + j) * 32 + kb);
      const float4 a0 = uv[0], a1 = uv[1];
      utpc[0]=a0.x; utpc[1]=a0.y; utpc[2]=a0.z; utpc[3]=a0.w;
      utpc[4]=a1.x; utpc[5]=a1.y; utpc[6]=a1.z; utpc[7]=a1.w; }
    const float md  = stats[j],       isd = stats[256 + j];
    const float mr  = stats[512 + j], isr = stats[768 + j];

    bf16x8 whi[2], wlo[2];               // W2 hi/lo split: f32-accurate product
#pragma unroll
    for (int mt = 0; mt < 2; ++mt) {
        const int m = m0 + (mt << 4);
#pragma unroll
        for (int e = 0; e < 8; ++e) {
            const float wv = W2p[(kb + e) * 32 + m];
            const short h16 = f2bf(wv);
            whi[mt][e] = h16;
            wlo[mt][e] = f2bf(wv - bf2f(h16));
        }
    }
    const float b2c[2] = { b2p[m0], b2p[m0 + 16] };
    const bool mt1ok = (m0 < 14);        // m = m0+16 valid iff < 30

    float accp[2][4];
#pragma unroll
    for (int mt = 0; mt < 2; ++mt)
#pragma unroll
        for (int r = 0; r < 4; ++r) accp[mt][r] = 0.0f;

    const float* dptr = adj_dist   + (((b << 8) + i0) << 8) + j;
    const float* rptr = adj_direct + (((b << 8) + i0) << 8) + j;
    float dN = dptr[0], rN = rptr[0];

#pragma unroll 1
    for (int i = 0; i < 16; ++i) {
        const float dv = dN, rv = rN;
        if (i + 1 < 16) { dN = dptr[(i + 1) << 8]; rN = rptr[(i + 1) << 8]; }

        float usc[8];
        { const float4* uv = (const float4*)&us_s[i][kb];
          float4 a0 = uv[0], a1 = uv[1];
          usc[0]=a0.x; usc[1]=a0.y; usc[2]=a0.z; usc[3]=a0.w;
          usc[4]=a1.x; usc[5]=a1.y; usc[6]=a1.z; usc[7]=a1.w; }

        const bool  a  = (dv != 0.0f);
        const float dn = (dv - md) * isd;
        const float rn = (rv - mr) * isr;

        float h[8];
#pragma unroll
        for (int e = 0; e < 8; ++e) {
            float z = a ? (usc[e] + utpc[e]) : b1c[e];
            z = fmaf(dn, r26c[e], z);
            z = fmaf(rn, r28c[e], z);
            h[e] = sig(z);
        }
        union { bf16x8 v; unsigned u[4]; } af;
#pragma unroll
        for (int p = 0; p < 4; ++p) af.u[p] = pkbf(h[2*p], h[2*p+1]);

        float msum0 = 0.0f, msum1 = 0.0f;
#pragma unroll
        for (int mt = 0; mt < 2; ++mt) {
            f32x4 d4 = { b2c[mt], b2c[mt], b2c[mt], b2c[mt] };
            d4 = __builtin_amdgcn_mfma_f32_16x16x32_bf16(af.v, wlo[mt], d4, 0, 0, 0);
            d4 = __builtin_amdgcn_mfma_f32_16x16x32_bf16(af.v, whi[mt], d4, 0, 0, 0);
#pragma unroll
            for (int r = 0; r < 4; ++r) {
                float e = sig(d4[r]);
                if (mt == 1 && !mt1ok) e = 0.0f;
                accp[mt][r] += e;
                if (mt == 0) msum0 += e; else msum1 += e;
            }
        }
        // minus partial: reduce over the 4 k-groups -> 16-j wave total per m
        msum0 += __shfl_xor(msum0, 16); msum0 += __shfl_xor(msum0, 32);
        msum1 += __shfl_xor(msum1, 16); msum1 += __shfl_xor(msum1, 32);
        if (l < 16) { pool.mins[i][w][l] = msum0; pool.mins[i][w][l + 16] = msum1; }
    }
    __syncthreads();

    // minus flush: partial over this block's 64 j -> [b][jq][m][n=i0+ii]
    for (int idx = t; idx < 512; idx += 256) {
        const int ii = idx >> 5, m = idx & 31;
        const float s = pool.mins[ii][0][m] + pool.mins[ii][1][m]
                      + pool.mins[ii][2][m] + pool.mins[ii][3][m];
        minusv[(((((b << 2) + jq) << 5) + m) << 8) + i0 + ii] = s;
    }
    __syncthreads();   // pool reuse boundary: mins -> ldst

    // plus: transpose through LDS then coalesced store (64-float rows per m)
#pragma unroll
    for (int mt = 0; mt < 2; ++mt) {
        const int m = m0 + (mt << 4);
        if (m < 30) {
#pragma unroll
            for (int r = 0; r < 4; ++r) {
                const int jl = (w << 4) + (g << 2) + r;   // 0..63
                pool.ldst[m][jl] = accp[mt][r];
            }
        }
    }
    __syncthreads();
    { const int base = ((b << 4) + it) << 13;     // (b*16+it)*32*256
      for (int idx = t; idx < 1920; idx += 256) {
          const int m = idx >> 6, jl = idx & 63;
          plus[base + (m << 8) + (jq << 6) + jl] = pool.ldst[m][jl];
      }
    }
}

// ---- K4: reduce partials + node MLP, fused; grid = BB*8 ----
__global__ __launch_bounds__(256) void reduce_out_kernel(
    const float* __restrict__ plus, const float* __restrict__ minusv,
    const float* __restrict__ W3, const float* __restrict__ b3,
    float* __restrict__ out)
{
    __shared__ float agg_s[32][36];
    const int b  = blockIdx.x >> 3;
    const int nh = blockIdx.x & 7;
    const int t  = threadIdx.x;

    if (t < 240) {
        const int m  = t / 8;            // 0..29
        const int n4 = t % 8;            // float4 group within 32 n
        f32x4 acc = {0.f, 0.f, 0.f, 0.f};
#pragma unroll 1
        for (int it = 0; it < 16; ++it)
            acc += *(const f32x4*)(plus + (((b << 4) + it) << 13)
                                   + (m << 8) + (nh << 5) + (n4 << 2));
#pragma unroll
        for (int jq = 0; jq < 4; ++jq)
            acc -= *(const f32x4*)(minusv + (((((b << 2) + jq) << 5) + m) << 8)
                                   + (nh << 5) + (n4 << 2));
#pragma unroll
        for (int q = 0; q < 4; ++q) agg_s[(n4 << 2) + q][m] = acc[q];
    }
    __syncthreads();

    for (int task = t; task < 384; task += 256) {
        const int n2 = task / 12, o = task % 12;
        float z = b3[o];
#pragma unroll
        for (int m = 0; m < 30; ++m) z = fmaf(agg_s[n2][m], W3[m * 12 + o], z);
        out[(((b << 8) + (nh << 5) + n2) * 12) + o] = sig(z);
    }
}

extern "C" void kernel_launch(void* const* d_in, const int* in_sizes, int n_in,
                              void* d_out, int out_size, void* d_ws, size_t ws_size,
                              hipStream_t stream)
{
    const float* x    = (const float*)d_in[0];
    const float* adjd = (const float*)d_in[1];
    const float* adjr = (const float*)d_in[2];
    const float* W1   = (const float*)d_in[5];
    const float* b1   = (const float*)d_in[6];
    const float* W2   = (const float*)d_in[7];
    const float* b2   = (const float*)d_in[8];
    const float* W3   = (const float*)d_in[9];
    const float* b3   = (const float*)d_in[10];
    float* ws  = (float*)d_ws;
    float* out = (float*)d_out;

    pre_kernel<<<1280, 256, 0, stream>>>(adjd, adjr, x, W1, b1,
                                         ws + WS_PART, ws + WS_USG, ws + WS_UTPG);
    finalize_kernel<<<9, 256, 0, stream>>>(ws + WS_PART, W2, b2,
                                           ws + WS_STATS, ws + WS_W2P, ws + WS_B2P);
    edge_mfma_kernel<<<2048, 256, 0, stream>>>(adjd, adjr, W1, b1,
                                               ws + WS_USG, ws + WS_UTPG,
                                               ws + WS_STATS, ws + WS_W2P,
                                               ws + WS_B2P, ws + WS_PLUS,
                                               ws + WS_MIN);
    reduce_out_kernel<<<BB * 8, 256, 0, stream>>>(ws + WS_PLUS, ws + WS_MIN,
                                                  W3, b3, out);
}